// Round 9
// baseline (263.846 us; speedup 1.0000x reference)
//
#include <hip/hip_runtime.h>
#include <cstdint>
#include <cstddef>

// ---------------------------------------------------------------------------
// GatingNetwork r9: r8 skeleton (16x16x32 Markidis-3, rolling 2-set B pipe,
// raw lgkm-only barriers, K=64 supers, 4 waves/SIMD) + two r8-counter fixes:
// (1) fragment-major A-slab [kslot][row][8h] -> conflict-free ds_read AND
//     ds_write (r8 stride-72 layout was an 8-way bank conflict per A-read),
// (2) third staged image ahs = ah*2^-8 (exact pow2) -> removes 32 pk_mul per
//     chunk per wave from the main loop (the dominant in-loop VALU).
// Numerics (r1-r8 verified): A=64x hi/lo fp16, B=64w hi/lo fp16 (lo x2^8);
// 3-product MFMA; h at scale 2^12; fused LN/erf-GELU/top2/lb-loss.
// ---------------------------------------------------------------------------

typedef _Float16 f16;
typedef _Float16 f16x8 __attribute__((ext_vector_type(8)));
typedef float f32x4 __attribute__((ext_vector_type(4)));

#define B_ROWS 65536
#define D_DIM 1024
#define H_DIM 512
#define E_DIM 8
#define BM 64
#define BK 32
#define THREADS 512
#define NSUPER 16                        // 16 supers x K64 (2 chunks each)
#define IMGH 4096                        // halves per image per buffer (8 kslot x 64 row x 8)
#define BUFH3 12288                      // 3 images per buffer
#define IMG_CH (H_DIM * BK)              // 16384 halves per K-chunk B image
#define IMG_TOTAL (32 * IMG_CH)          // 1 MB per image
#define GACC_OFF ((size_t)2 * IMG_TOTAL * sizeof(f16))  // 2 MB

// ---- prep: split W1 into fp16 hi/lo images in MFMA B-fragment order --------
__global__ void prep_split(const float* __restrict__ W1,
                           f16* __restrict__ wh, f16* __restrict__ wl) {
  int id = blockIdx.x * 256 + threadIdx.x;   // 65536 threads
  int h = id & (H_DIM - 1);
  int kg = id >> 9;                          // 0..127
  int c = kg >> 2;
  int kk0 = (kg & 3) * 8;
  int k0 = kg * 8;
  f16x8 hv, lv;
#pragma unroll
  for (int j = 0; j < 8; ++j) {
    float v = W1[(size_t)(k0 + j) * H_DIM + h] * 64.0f;
    f16 hi = (f16)v;
    hv[j] = hi;
    lv[j] = (f16)((v - (float)hi) * 256.0f);  // residual pre-scaled 2^8
  }
  size_t o = (size_t)c * IMG_CH + (size_t)h * BK + kk0;
  *(f16x8*)&wh[o] = hv;
  *(f16x8*)&wl[o] = lv;
}

__global__ void zero_acc(float* __restrict__ acc) {
  if (threadIdx.x < 16) acc[threadIdx.x] = 0.0f;
}

// ---- main fused kernel -----------------------------------------------------
__global__ __launch_bounds__(THREADS, 4) void fused_main(
    const float* __restrict__ x,
    const f16* __restrict__ wh, const f16* __restrict__ wl,
    const float* __restrict__ b1, const float* __restrict__ lnw,
    const float* __restrict__ lnb, const float* __restrict__ W2,
    const float* __restrict__ b2, float* __restrict__ out,
    float* __restrict__ gacc) {
  // GEMM: 2 buffers x 3 images x 8192 B = 49152 B. Epilogue overlays [0,45632).
  __shared__ __align__(16) char pool[49152];
  f16* sx = (f16*)pool;

  const int tid = threadIdx.x;
  const int lane = tid & 63;
  const int wv = tid >> 6;        // 0..7 : wave owns cols wv*64..+63, all 64 rows
  const int l15 = lane & 15;
  const int l4 = lane >> 4;       // 0..3
  const int64_t row0 = (int64_t)blockIdx.x * BM;

  // staging: thread stages row tid>>3, kslot tid&7 (8 contiguous k) per super
  const int srow = tid >> 3;
  const int kslot = tid & 7;
  const int swo = kslot * 512 + srow * 8;          // halves, fragment-major
  const float* xbase = x + (row0 + srow) * D_DIM + kslot * 8;

  // A-read lane offset within a buffer (fragment-major): kslot=ch*4+l4, row
  const int aro = l4 * 512 + l15 * 8;              // + ch*2048 + m*128 + buf

  // B lane base (fragment-order image, r2-verified)
  const f16* whp = wh + (wv * 64 + l15) * BK + l4 * 8;

  f32x4 acc[4][4];
#pragma unroll
  for (int m = 0; m < 4; ++m)
#pragma unroll
    for (int n = 0; n < 4; ++n) acc[m][n] = (f32x4){0.f, 0.f, 0.f, 0.f};

  // two half-chunk B register sets: [set][0..1]=hi frags, [2..3]=lo frags
  f16x8 setB[2][4];

#define ISSUE(si, C, half)                                                    \
  do {                                                                        \
    const f16* p = whp + (size_t)((C) & 31) * IMG_CH + (half) * 1024;         \
    setB[si][0] = *(const f16x8*)(p);                                         \
    setB[si][1] = *(const f16x8*)(p + 512);                                   \
    setB[si][2] = *(const f16x8*)(p + IMG_TOTAL);                             \
    setB[si][3] = *(const f16x8*)(p + IMG_TOTAL + 512);                       \
  } while (0)

  // per (m,ch): 3 conflict-free ds_read_b128 (ah, al, ahs) -> 6 MFMA,
  // alternate accumulators to space dependent MFMAs.
#define CHUNK_HALF(si, nh, ch, bufv)                                          \
  do {                                                                        \
    __builtin_amdgcn_s_setprio(1);                                            \
    _Pragma("unroll") for (int m = 0; m < 4; ++m) {                           \
      const int ao = (bufv)*BUFH3 + (ch)*2048 + m * 128 + aro;                \
      f16x8 ah = *(const f16x8*)&sx[ao];                                      \
      f16x8 al = *(const f16x8*)&sx[ao + IMGH];                               \
      f16x8 as_ = *(const f16x8*)&sx[ao + 2 * IMGH];                          \
      acc[m][(nh)*2 + 0] = __builtin_amdgcn_mfma_f32_16x16x32_f16(            \
          ah, setB[si][0], acc[m][(nh)*2 + 0], 0, 0, 0);                      \
      acc[m][(nh)*2 + 1] = __builtin_amdgcn_mfma_f32_16x16x32_f16(            \
          ah, setB[si][1], acc[m][(nh)*2 + 1], 0, 0, 0);                      \
      acc[m][(nh)*2 + 0] = __builtin_amdgcn_mfma_f32_16x16x32_f16(            \
          al, setB[si][0], acc[m][(nh)*2 + 0], 0, 0, 0);                      \
      acc[m][(nh)*2 + 1] = __builtin_amdgcn_mfma_f32_16x16x32_f16(            \
          al, setB[si][1], acc[m][(nh)*2 + 1], 0, 0, 0);                      \
      acc[m][(nh)*2 + 0] = __builtin_amdgcn_mfma_f32_16x16x32_f16(            \
          as_, setB[si][2], acc[m][(nh)*2 + 0], 0, 0, 0);                     \
      acc[m][(nh)*2 + 1] = __builtin_amdgcn_mfma_f32_16x16x32_f16(            \
          as_, setB[si][3], acc[m][(nh)*2 + 1], 0, 0, 0);                     \
    }                                                                         \
    __builtin_amdgcn_s_setprio(0);                                            \
  } while (0)

#define WRITE_SLAB(bufv)                                                      \
  do {                                                                        \
    float vv[8] = {xv0.x, xv0.y, xv0.z, xv0.w, xv1.x, xv1.y, xv1.z, xv1.w};   \
    f16x8 hv, lv, sv;                                                         \
    _Pragma("unroll") for (int q = 0; q < 8; ++q) {                           \
      float t = vv[q] * 64.0f;                                                \
      f16 hh = (f16)t;                                                        \
      hv[q] = hh;                                                             \
      lv[q] = (f16)(t - (float)hh);                                           \
      sv[q] = hh * (f16)0.00390625f;                                          \
    }                                                                         \
    *(f16x8*)&sx[(bufv)*BUFH3 + swo] = hv;                                    \
    *(f16x8*)&sx[(bufv)*BUFH3 + IMGH + swo] = lv;                             \
    *(f16x8*)&sx[(bufv)*BUFH3 + 2 * IMGH + swo] = sv;                         \
  } while (0)

  // raw barrier: drain only LDS ops, keep global loads in flight (T4)
#define SLAB_BARRIER()                                                        \
  do {                                                                        \
    asm volatile("s_waitcnt lgkmcnt(0)" ::: "memory");                        \
    __builtin_amdgcn_s_barrier();                                             \
    __builtin_amdgcn_sched_barrier(0);                                        \
  } while (0)

  // ---- prologue: slab super0, B sets for chunk0 halves, xv <- super1 ------
  float4 xv0 = *(const float4*)(xbase);
  float4 xv1 = *(const float4*)(xbase + 4);
  WRITE_SLAB(0);
  ISSUE(0, 0, 0);
  ISSUE(1, 0, 1);
  xv0 = *(const float4*)(xbase + 64);
  xv1 = *(const float4*)(xbase + 68);
  SLAB_BARRIER();

  for (int s = 0; s < NSUPER; ++s) {
    const int buf = s & 1;
    CHUNK_HALF(0, 0, 0, buf);     // chunk 2s,   frags n0/n1
    ISSUE(0, 2 * s + 1, 0);       // refill set0 for chunk 2s+1
    CHUNK_HALF(1, 1, 0, buf);     // chunk 2s,   frags n2/n3
    ISSUE(1, 2 * s + 1, 1);       // refill set1 for chunk 2s+1
    CHUNK_HALF(0, 0, 1, buf);     // chunk 2s+1, frags n0/n1
    ISSUE(0, 2 * s + 2, 0);       // refill set0 for chunk 2s+2
    CHUNK_HALF(1, 1, 1, buf);     // chunk 2s+1, frags n2/n3
    ISSUE(1, 2 * s + 2, 1);       // refill set1 for chunk 2s+2
    WRITE_SLAB(buf ^ 1);          // slab for super s+1 (xv loaded last iter)
    xv0 = *(const float4*)(xbase + (((s + 2) & 15) * 64));   // x for super s+2
    xv1 = *(const float4*)(xbase + (((s + 2) & 15) * 64) + 4);
    SLAB_BARRIER();
  }
#undef ISSUE
#undef CHUNK_HALF
#undef WRITE_SLAB
#undef SLAB_BARRIER
  __syncthreads();  // full drain before overlaying epilogue LDS

  // ---------------- epilogue (h at scale 2^12 in acc; r6-verified) ----------
  float* eW2T = (float*)pool;              // [512][12] padded = 24576 B
  float* eStat = (float*)(pool + 24576);   // [8][64][2] = 4096 B
  float* eLog = (float*)(pool + 28672);    // [8][64][8] = 16384 B
  float* eMu = (float*)(pool + 45056);     // [64]
  float* eRs = (float*)(pool + 45312);     // [64]
  float* eFP = (float*)(pool + 45568);     // [16]

  // stage W2 (each thread owns one column h = tid)
  {
    float4 wa = *(const float4*)&W2[tid * 8];
    float4 wb = *(const float4*)&W2[tid * 8 + 4];
    *(float4*)&eW2T[tid * 12] = wa;
    *(float4*)&eW2T[tid * 12 + 4] = wb;
  }
  if (tid < 16) eFP[tid] = 0.0f;

  // h += b1 (scaled); per-column params from L2 (tiny + hot)
  float bb[4], lw[4], lb[4];
#pragma unroll
  for (int n = 0; n < 4; ++n) {
    int col = wv * 64 + n * 16 + l15;
    bb[n] = b1[col] * 4096.0f;
    lw[n] = lnw[col];
    lb[n] = lnb[col];
#pragma unroll
    for (int m = 0; m < 4; ++m)
#pragma unroll
      for (int r = 0; r < 4; ++r) acc[m][n][r] += bb[n];
  }

  // row stats: partial over this wave's 64 cols, deterministic combine
#pragma unroll
  for (int m = 0; m < 4; ++m) {
    float s1[4] = {0, 0, 0, 0};
    float s2[4] = {0, 0, 0, 0};
#pragma unroll
    for (int n = 0; n < 4; ++n)
#pragma unroll
      for (int r = 0; r < 4; ++r) {
        float vv = acc[m][n][r];
        s1[r] += vv;
        s2[r] = fmaf(vv, vv, s2[r]);
      }
#pragma unroll
    for (int d = 1; d < 16; d <<= 1)
#pragma unroll
      for (int r = 0; r < 4; ++r) {
        s1[r] += __shfl_xor(s1[r], d);
        s2[r] += __shfl_xor(s2[r], d);
      }
    if (l15 == 0) {
      int rb = m * 16 + l4 * 4;
#pragma unroll
      for (int r = 0; r < 4; ++r) {
        eStat[(wv * 64 + rb + r) * 2 + 0] = s1[r];
        eStat[(wv * 64 + rb + r) * 2 + 1] = s2[r];
      }
    }
  }
  __syncthreads();
  if (tid < BM) {
    float s1 = 0.0f, s2 = 0.0f;
#pragma unroll
    for (int w = 0; w < 8; ++w) {
      s1 += eStat[(w * 64 + tid) * 2 + 0];
      s2 += eStat[(w * 64 + tid) * 2 + 1];
    }
    float mu = s1 * (1.0f / 512.0f);
    float var = s2 * (1.0f / 512.0f) - mu * mu;
    eMu[tid] = mu;
    eRs[tid] = 1.0f / sqrtf(var + (1e-5f * 4096.0f * 4096.0f));
  }
  __syncthreads();

  // LN + exact-erf GELU + per-wave partial logits (per-r accumulation)
#pragma unroll
  for (int m = 0; m < 4; ++m) {
    int rb = m * 16 + l4 * 4;
#pragma unroll
    for (int r = 0; r < 4; ++r) {
      float mu_r = eMu[rb + r];
      float rs_r = eRs[rb + r];
      float lg[8];
#pragma unroll
      for (int e = 0; e < 8; ++e) lg[e] = 0.0f;
#pragma unroll
      for (int n = 0; n < 4; ++n) {
        int col = wv * 64 + n * 16 + l15;
        float hn = (acc[m][n][r] - mu_r) * rs_r;
        float y = fmaf(hn, lw[n], lb[n]);
        float g = 0.5f * y * (1.0f + erff(y * 0.70710678118654752440f));
        float4 w0 = *(const float4*)&eW2T[col * 12];
        float4 w1 = *(const float4*)&eW2T[col * 12 + 4];
        lg[0] = fmaf(g, w0.x, lg[0]);
        lg[1] = fmaf(g, w0.y, lg[1]);
        lg[2] = fmaf(g, w0.z, lg[2]);
        lg[3] = fmaf(g, w0.w, lg[3]);
        lg[4] = fmaf(g, w1.x, lg[4]);
        lg[5] = fmaf(g, w1.y, lg[5]);
        lg[6] = fmaf(g, w1.z, lg[6]);
        lg[7] = fmaf(g, w1.w, lg[7]);
      }
#pragma unroll
      for (int d = 1; d < 16; d <<= 1)
#pragma unroll
        for (int e = 0; e < 8; ++e) lg[e] += __shfl_xor(lg[e], d);
      if (l15 == 0) {
#pragma unroll
        for (int e = 0; e < 8; ++e) eLog[(wv * 64 + rb + r) * 8 + e] = lg[e];
      }
    }
  }
  __syncthreads();

  // top-2 + sparse softmax + write + load-balance partials
  if (tid < BM) {
    float v[8];
#pragma unroll
    for (int e = 0; e < 8; ++e) {
      float s = b2[e];
#pragma unroll
      for (int w = 0; w < 8; ++w) s += eLog[(w * 64 + tid) * 8 + e];
      v[e] = s;
    }
    float m1 = v[0];
    int i1 = 0;
#pragma unroll
    for (int e = 1; e < 8; ++e)
      if (v[e] > m1) { m1 = v[e]; i1 = e; }   // strict >: lowest index wins ties
    float m2 = -3.0e38f;
    int i2 = -1;
#pragma unroll
    for (int e = 0; e < 8; ++e)
      if (e != i1 && v[e] > m2) { m2 = v[e]; i2 = e; }
    float dd = expf(m2 - m1);
    float inv = 1.0f / (1.0f + dd);
    float wA = inv, wB = dd * inv;
    float o[8];
#pragma unroll
    for (int e = 0; e < 8; ++e)
      o[e] = (e == i1) ? wA : ((e == i2) ? wB : 0.0f);
    float4* op = (float4*)&out[(row0 + tid) * 8];
    op[0] = (float4){o[0], o[1], o[2], o[3]};
    op[1] = (float4){o[4], o[5], o[6], o[7]};
    atomicAdd(&eFP[i1], 1.0f);
    atomicAdd(&eFP[i2], 1.0f);
    atomicAdd(&eFP[8 + i1], wA);
    atomicAdd(&eFP[8 + i2], wB);
  }
  __syncthreads();
  if (tid < 16) atomicAdd(&gacc[tid], eFP[tid]);
}

// ---- finalize load-balance loss --------------------------------------------
__global__ void lb_final(const float* __restrict__ gacc, float* __restrict__ out) {
  if (threadIdx.x == 0) {
    const float invB = 1.0f / 65536.0f;
    float s = 0.0f;
#pragma unroll
    for (int e = 0; e < 8; ++e) s += (gacc[e] * invB) * (gacc[8 + e] * invB);
    out[(size_t)B_ROWS * E_DIM] = 0.01f * 8.0f * s;
  }
}

// ---- launch ----------------------------------------------------------------
extern "C" void kernel_launch(void* const* d_in, const int* in_sizes, int n_in,
                              void* d_out, int out_size, void* d_ws, size_t ws_size,
                              hipStream_t stream) {
  (void)in_sizes; (void)n_in; (void)out_size; (void)ws_size;
  const float* x = (const float*)d_in[0];
  const float* W1 = (const float*)d_in[1];
  const float* b1 = (const float*)d_in[2];
  const float* lnw = (const float*)d_in[3];
  const float* lnb = (const float*)d_in[4];
  const float* W2 = (const float*)d_in[5];
  const float* b2 = (const float*)d_in[6];
  float* out = (float*)d_out;
  f16* wh = (f16*)d_ws;
  f16* wl = wh + IMG_TOTAL;
  float* gacc = (float*)((char*)d_ws + GACC_OFF);  // ws needs ~2.1 MB

  zero_acc<<<1, 64, 0, stream>>>(gacc);
  prep_split<<<(D_DIM * H_DIM / 8) / 256, 256, 0, stream>>>(W1, wh, wl);
  fused_main<<<B_ROWS / BM, THREADS, 0, stream>>>(x, wh, wl, b1, lnw, lnb, W2, b2,
                                                  out, gacc);
  lb_final<<<1, 64, 0, stream>>>(gacc, out);
}